// Round 1
// 492.756 us; speedup vs baseline: 1.0586x; 1.0586x over previous
//
#include <hip/hip_runtime.h>
#include <math.h>

#pragma clang fp contract(off)

#define NBINS 36
#define PS 32

// Slim branchless f64 atan2, rounded to f32 (absmax 0.0 R5/R6).
// R8: single-NR division (rcp_f64 err e -> r0 err ~e^2; residual-corrected
// quotient error ~ q*(e_r*e_q0) + 0.5ulp stays ~0.5ulp for any e <= 2^-20),
// and p/atc_lo folded into one fma. Same <=~0.5ulp-of-f64 class as R7.
__device__ __forceinline__ float atan2_np(float fy, float fx)
{
    const double aT0  =  3.33333333333329318027e-01;
    const double aT1  = -1.99999999998764832476e-01;
    const double aT2  =  1.42857142725034663711e-01;
    const double aT3  = -1.11111104054623557880e-01;
    const double aT4  =  9.09088713343650656196e-02;
    const double aT5  = -7.69187620504482999495e-02;
    const double aT6  =  6.66107313738753120669e-02;
    const double aT7  = -5.83357013379057348645e-02;
    const double aT8  =  4.97687799461593236017e-02;
    const double aT9  = -3.65315727442169155270e-02;
    const double aT10 =  1.62858201153657823623e-02;

    float axf = fabsf(fx), ayf = fabsf(fy);
    float uf = fmaxf(axf, ayf), vf = fminf(axf, ayf);
    bool g1 = vf >= 0.41421356f * uf;          // ~tan(pi/8); either branch valid near cut

    double u = (double)uf, v = (double)vf;
    double c      = g1 ? 1.0 : 0.0;
    double atc_hi = g1 ? 7.85398163397448278999e-01 : 0.0;
    double atc_lo = g1 ? 3.06161699786838301793e-17 : 0.0;

    double num = fma(-c, u, v);                // c=0: exactly v
    double den = fma(c, v, u);                 // c=0: exactly u

    double r0 = __builtin_amdgcn_rcp(den);
    r0 = fma(fma(-den, r0, 1.0), r0, r0);      // single NR: r0 err ~max(e^2, 2^-53)
    double q0 = num * r0;
    double xq = fma(fma(-den, q0, num), r0, q0);   // residual-corrected, ~0.5 ulp
    // xq in [-0.1716, 0.4143] — inside fdlibm poly range [0, 0.4375]

    double z = xq * xq;
    double w = z * z;
    double s1_ = z * fma(w, fma(w, fma(w, fma(w, fma(w, aT10, aT8), aT6), aT4), aT2), aT0);
    double s2_ = w * fma(w, fma(w, fma(w, fma(w, aT9, aT7), aT5), aT3), aT1);
    double T   = fma(xq, s1_ + s2_, -atc_lo);      // == (p - atc_lo) to ~0.5ulp
    double res = atc_hi - (T - xq);                // angle of (u,v)

    double res2 = (1.57079632679489655800e+00 - res) + 6.12323399573676603587e-17;
    res = (ayf > axf) ? res2 : res;                // angle of (|x|,|y|)
    double res3 = (3.14159265358979311600e+00 - res) + 1.22464679914735317723e-16;
    res = (fx < 0.0f) ? res3 : res;                // x<0 half-plane
    res = copysign(res, (double)fy);
    return (float)res;
}

// DPP lane-shift helpers (VALU, no LDS): value of lane-1 / lane+1 within
// 16-lane DPP rows. Lanes receiving cross-row garbage are exactly the
// edge-clamped ones (cb==0 / cb==28), overridden by the caller's select.
__device__ __forceinline__ float dpp_prev(float x) {
    int i = __builtin_bit_cast(int, x);
    int r = __builtin_amdgcn_update_dpp(i, i, 0x111, 0xf, 0xf, false); // row_shr:1
    return __builtin_bit_cast(float, r);
}
__device__ __forceinline__ float dpp_next(float x) {
    int i = __builtin_bit_cast(int, x);
    int r = __builtin_amdgcn_update_dpp(i, i, 0x101, 0xf, 0xf, false); // row_shl:1
    return __builtin_bit_cast(float, r);
}

// One block = one patch. Bit-exact replication of the numpy reference:
//  - conv taps pre-scaled (exact pow2 products), summed ascending (kh,kw)
//  - mag = sqrt((gx*gx + gy*gy) + eps), contraction off
//  - atan2: slim f64 (above), rounded to f32
//  - /2pi division: Markstein (rcp + fma correction) — 1-ulp-rare class
//  - histogram: per-bin sequential add chain in pixel order, w0 pass then
//    w1 pass (np.add.at semantics), via order-preserving counting sort.
// R8 vs R7:
//  - tile column-XOR swizzle (col ^ (row&7)<<2): the float4 store and the 3
//    window ds_read_b128 were 8-way bank-conflicted (8 lanes share cb across
//    8 rows); swizzle spreads them over 8 bank quads. DPP edge fills are
//    unaffected (lane+-1 reads its own float4 correctly from the same row).
//  - prefix-popcount loop batched 8-wide (was #pragma unroll 1 -> 32 serial
//    dependent LDS round-trips on wave 0); chains unrolled 4 (order kept).
__global__ __launch_bounds__(256)
void patch_orient_kernel(const float* __restrict__ patches, float* __restrict__ out)
{
    __shared__ __align__(16) float tile[PS * PS];      // 4 KiB, column-swizzled
    __shared__ unsigned bm[PS][NBINS];                 // 4.5 KiB  bm[row][bin]
    __shared__ unsigned short pref[PS][NBINS];         // 2.25 KiB word-prefix popcounts
    __shared__ unsigned short cnt[NBINS];
    __shared__ unsigned short start[NBINS];
    __shared__ __align__(16) float s0[1024];           // w0 sorted by (bin, pixel)
    __shared__ __align__(16) float s1[1024];           // w1, same permutation
    __shared__ float hsm[NBINS];

    const int t = threadIdx.x;
    const int b = blockIdx.x;
    const float* p = patches + (size_t)b * (PS * PS);

    #pragma unroll
    for (int i = t; i < PS * NBINS; i += 256) ((unsigned*)bm)[i] = 0u;

    // thread t owns pixels 4t..4t+3: row = t>>3, cols cb..cb+3
    const int row = t >> 3;
    const int cb  = (t & 7) << 2;
    const int rm  = (row == 0)  ? 0  : row - 1;
    const int rp  = (row == 31) ? 31 : row + 1;

    // coalesced 4 KiB load, swizzled store (conflict-free b128)
    *((float4*)&tile[(row << 5) | (cb ^ ((row & 7) << 2))]) = ((const float4*)p)[t];
    __syncthreads();

    // 3 rows x 6 cols window: one swizzled b128 per row + DPP for edge cols
    float win[3][6];
    {
        const int rows[3] = {rm, row, rp};
        #pragma unroll
        for (int r = 0; r < 3; ++r) {
            const int rr = rows[r];
            float4 v = *((const float4*)&tile[(rr << 5) | (cb ^ ((rr & 7) << 2))]);
            float lf = dpp_prev(v.w);              // lane-1's col cb-1
            float rt = dpp_next(v.x);              // lane+1's col cb+4
            win[r][0] = (cb == 0)  ? v.x : lf;     // edge clamp col 0
            win[r][1] = v.x; win[r][2] = v.y; win[r][3] = v.z; win[r][4] = v.w;
            win[r][5] = (cb == 28) ? v.w : rt;     // edge clamp col 31
        }
    }

    const float TWO_PI = 6.2831853071795864769f;   // f32(2*pi) == 2*f32(pi)
    const float PI_F   = 3.14159265358979323846f;
    const float INV2PI = 0.15915493667125701904f;  // RN_f32(1 / f32(2*pi))

    const unsigned bitbase = 1u << cb;

    float w0r[4], w1r[4];
    int   binr[4];

    #pragma unroll
    for (int i = 0; i < 4; ++i) {
        float A = win[0][i], B = win[0][i + 1], C = win[0][i + 2];
        float D = win[1][i],                    F = win[1][i + 2];
        float G = win[2][i], H = win[2][i + 1], I = win[2][i + 2];

        // pre-scaled taps (exact pow2 products), ascending (kh,kw) order
        float gx = -0.125f * A;
        gx += 0.125f  * C;
        gx += -0.25f  * D;
        gx += 0.25f   * F;
        gx += -0.125f * G;
        gx += 0.125f  * I;

        float gy = -0.125f * A;
        gy += -0.25f  * B;
        gy += -0.125f * C;
        gy += 0.125f  * G;
        gy += 0.25f   * H;
        gy += 0.125f  * I;

        float m1 = gx * gx;
        float m2 = gy * gy;
        float s  = m1 + m2;
        s = s + 1e-8f;
        float mag = sqrtf(s);                      // IEEE sqrt

        float gxe = gx + 1e-8f;
        float at  = atan2_np(gy, gxe);
        float ori = at + TWO_PI;
        float xn  = 36.0f * (ori + PI_F);
        // Markstein correctly-rounded-division surrogate for xn / TWO_PI
        float q1m = xn * INV2PI;
        float obig = fmaf(fmaf(-TWO_PI, q1m, xn), INV2PI, q1m);
        float bo0  = floorf(obig);
        float wo1  = obig - bo0;                   // exact (Sterbenz)

        // bo0 provably in [35, 72]; fold to [0,36)
        int bi0 = (int)bo0 - 36;
        if (bi0 < 0)   bi0 += 36;                  // 35 -> 35
        if (bi0 >= 36) bi0 -= 36;                  // 72 -> 0

        w0r[i]  = (1.0f - wo1) * mag;
        w1r[i]  = wo1 * mag;
        binr[i] = bi0;
        atomicOr(&bm[row][bi0], bitbase << i);
    }
    __syncthreads();

    // wave 0: per-bin word-prefix popcounts + counts + bin-start prefix.
    // Loads batched 8-wide so the compiler pipelines the LDS round-trips
    // (R7's #pragma unroll 1 serialized 32 dependent loads).
    if (t < 64) {
        unsigned run = 0;
        if (t < NBINS) {
            #pragma unroll
            for (int w = 0; w < PS; w += 8) {
                unsigned m0 = bm[w + 0][t], m1 = bm[w + 1][t];
                unsigned m2 = bm[w + 2][t], m3 = bm[w + 3][t];
                unsigned m4 = bm[w + 4][t], m5 = bm[w + 5][t];
                unsigned m6 = bm[w + 6][t], m7 = bm[w + 7][t];
                pref[w + 0][t] = (unsigned short)run; run += __popc(m0);
                pref[w + 1][t] = (unsigned short)run; run += __popc(m1);
                pref[w + 2][t] = (unsigned short)run; run += __popc(m2);
                pref[w + 3][t] = (unsigned short)run; run += __popc(m3);
                pref[w + 4][t] = (unsigned short)run; run += __popc(m4);
                pref[w + 5][t] = (unsigned short)run; run += __popc(m5);
                pref[w + 6][t] = (unsigned short)run; run += __popc(m6);
                pref[w + 7][t] = (unsigned short)run; run += __popc(m7);
            }
            cnt[t] = (unsigned short)run;
        }
        // exclusive prefix over bins (wave-wide shfl scan; lanes >=36 hold 0)
        unsigned v = run;
        #pragma unroll
        for (int d = 1; d < 64; d <<= 1) {
            unsigned o = (unsigned)__shfl_up((int)v, d);
            if (t >= d) v += o;
        }
        if (t < NBINS) start[t] = (unsigned short)(v - run);
    }
    __syncthreads();

    // scatter weights from registers into bin-sorted order (stable by pixel)
    #pragma unroll
    for (int i = 0; i < 4; ++i) {
        const int bi = binr[i];
        const unsigned lowmask = (bitbase << i) - 1u;
        const int pos = (int)start[bi] + (int)pref[row][bi]
                      + __popc(bm[row][bi] & lowmask);
        s0[pos] = w0r[i];
        s1[pos] = w1r[i];
    }
    __syncthreads();

    // exact np.add.at chains: bin t = (w0 run of bin t) then (w1 run of bin t-1)
    // unroll 4 (order preserved) to batch the LDS loads.
    if (t < NBINS) {
        float acc = 0.0f;
        {
            int i = start[t], en = i + cnt[t];
            for (; i + 3 < en; i += 4) {
                acc += s0[i]; acc += s0[i + 1]; acc += s0[i + 2]; acc += s0[i + 3];
            }
            for (; i < en; ++i) acc += s0[i];
        }
        {
            int t2 = (t == 0) ? NBINS - 1 : t - 1;
            int i = start[t2], en = i + cnt[t2];
            for (; i + 3 < en; i += 4) {
                acc += s1[i]; acc += s1[i + 1]; acc += s1[i + 2]; acc += s1[i + 3];
            }
            for (; i < en; ++i) acc += s1[i];
        }
        hsm[t] = acc * (1.0f / 1024.0f);           // /npix, exact pow2
    }
    __syncthreads();

    // parallel smoothing + butterfly argmax (min index on ties == np.argmax)
    if (t < 64) {
        float val = -1.0f;                          // all sm >= 0
        int   idx = t;
        if (t < NBINS) {
            int im_ = (t == 0)         ? NBINS - 1 : t - 1;
            int ip_ = (t == NBINS - 1) ? 0         : t + 1;
            float q0 = 0.33f * hsm[im_];
            float q1 = 0.34f * hsm[t];
            float q2 = 0.33f * hsm[ip_];
            float val_ = (q0 + q1) + q2;            // left-to-right, no FMA
            val = val_;
        }
        #pragma unroll
        for (int d = 1; d < 64; d <<= 1) {
            float ov = __shfl_xor(val, d);
            int   oi = __shfl_xor(idx, d);
            if (ov > val || (ov == val && oi < idx)) { val = ov; idx = oi; }
        }
        if (t == 0) {
            float t1 = TWO_PI * (float)idx;
            float t2 = t1 / 36.0f;
            float t3 = t2 - PI_F;
            out[b] = -t3;
        }
    }
}

extern "C" void kernel_launch(void* const* d_in, const int* in_sizes, int n_in,
                              void* d_out, int out_size, void* d_ws, size_t ws_size,
                              hipStream_t stream) {
    const float* patch = (const float*)d_in[0];
    float* out = (float*)d_out;
    const int B = in_sizes[0] / (PS * PS);   // 65536 patches
    patch_orient_kernel<<<B, 256, 0, stream>>>(patch, out);
}